// Round 11
// baseline (435.882 us; speedup 1.0000x reference)
//
#include <hip/hip_runtime.h>
#include <cstdint>

// ---- problem constants (MoEFeedForward: N=4096, D=1024, F=2048, E=8, top-2) ----
#define N_TOK 4096
#define D_MODEL 1024
#define D_FF 2048
#define D_GU 4096          // 2*D_FF: gate_up row space in w_gate_up
#define N_EXP 8

typedef __bf16 bf16;
typedef __bf16 bf16x8 __attribute__((ext_vector_type(8)));
typedef float f32x4 __attribute__((ext_vector_type(4)));

typedef __attribute__((address_space(1))) void v1_t;
typedef __attribute__((address_space(3))) void v3_t;

// async global->LDS raw copy, 16B/lane; dest = wave-uniform base + lane*16
__device__ __forceinline__ void cp16(void* lds, const void* g) {
  __builtin_amdgcn_global_load_lds((v1_t*)g, (v3_t*)lds, 16, 0, 0);
}

__device__ __forceinline__ f32x4 mfma16(bf16x8 a, bf16x8 b, f32x4 c) {
  return __builtin_amdgcn_mfma_f32_16x16x32_bf16(a, b, c, 0, 0, 0);
}

__device__ __forceinline__ bf16x8 cvt8(float4 a, float4 b) {
  bf16x8 v;
  v[0] = (bf16)a.x; v[1] = (bf16)a.y; v[2] = (bf16)a.z; v[3] = (bf16)a.w;
  v[4] = (bf16)b.x; v[5] = (bf16)b.y; v[6] = (bf16)b.z; v[7] = (bf16)b.w;
  return v;
}

// ======== router + wgu-cvt + wd-cvt fused launch ========
// blocks [0,128): routing + x fp32->bf16, emits tinfo for atomic-free combine.
// blocks [128,2048): wgu fp32->bf16.  blocks [2048,3072): wd fp32->bf16.
__global__ __launch_bounds__(256) void router_cvt_kernel(
    const float* __restrict__ x, const float* __restrict__ wr,
    int* __restrict__ counts, int* __restrict__ ids, float* __restrict__ wts,
    int4* __restrict__ tinfo, bf16* __restrict__ xb,
    const float* __restrict__ wgu, bf16* __restrict__ wgub,
    const float* __restrict__ wd, bf16* __restrict__ wdb)
{
  if (blockIdx.x >= 2048) {                     // ---- wd cvt riders (1024 blocks) ----
    const int n8 = (N_EXP * D_MODEL * D_FF) / 8;
    int i = (blockIdx.x - 2048) * 256 + threadIdx.x;
    for (; i < n8; i += 1024 * 256) {
      const float4* s = (const float4*)wd + 2 * (size_t)i;
      ((bf16x8*)wdb)[i] = cvt8(s[0], s[1]);
    }
    return;
  }
  if (blockIdx.x >= 128) {                      // ---- wgu cvt riders (1920 blocks) ----
    const int n8 = (N_EXP * D_GU * D_MODEL) / 8;
    int i = (blockIdx.x - 128) * 256 + threadIdx.x;
    for (; i < n8; i += 1920 * 256) {
      const float4* s = (const float4*)wgu + 2 * (size_t)i;
      ((bf16x8*)wgub)[i] = cvt8(s[0], s[1]);
    }
    return;
  }

  __shared__ int lcnt[N_EXP];
  __shared__ int gbase[N_EXP];
  __shared__ int s_e0[32], s_l0[32], s_e1[32], s_l1[32];
  __shared__ float s_p0[32], s_p1[32];

  const int tid  = threadIdx.x;
  const int wave = tid >> 6;
  const int lane = tid & 63;
  if (tid < N_EXP) lcnt[tid] = 0;
  __syncthreads();

  for (int it = 0; it < 8; ++it) {
    const int li = it * 4 + wave;                 // local token 0..31
    const int token = blockIdx.x * 32 + li;

    const float4* xrow = (const float4*)(x + (size_t)token * D_MODEL + lane * 16);
    float4 x0 = xrow[0], x1 = xrow[1], x2 = xrow[2], x3 = xrow[3];

    bf16* xd = xb + (size_t)token * D_MODEL + lane * 16;
    *(bf16x8*)xd       = cvt8(x0, x1);
    *(bf16x8*)(xd + 8) = cvt8(x2, x3);

    float logit[N_EXP];
#pragma unroll
    for (int e = 0; e < N_EXP; ++e) {
      const float4* wrow = (const float4*)(wr + e * D_MODEL + lane * 16);
      float4 w0 = wrow[0], w1 = wrow[1], w2 = wrow[2], w3 = wrow[3];
      float s = x0.x*w0.x + x0.y*w0.y + x0.z*w0.z + x0.w*w0.w
              + x1.x*w1.x + x1.y*w1.y + x1.z*w1.z + x1.w*w1.w
              + x2.x*w2.x + x2.y*w2.y + x2.z*w2.z + x2.w*w2.w
              + x3.x*w3.x + x3.y*w3.y + x3.z*w3.z + x3.w*w3.w;
#pragma unroll
      for (int m = 32; m >= 1; m >>= 1) s += __shfl_xor(s, m);
      logit[e] = fminf(fmaxf(s, -1e4f), 1e4f);    // reference CLAMP
    }

    if (lane == 0) {
      float mx = logit[0];
#pragma unroll
      for (int e = 1; e < N_EXP; ++e) mx = fmaxf(mx, logit[e]);
      float ex[N_EXP], sum = 0.f;
#pragma unroll
      for (int e = 0; e < N_EXP; ++e) { ex[e] = expf(logit[e] - mx); sum += ex[e]; }
      float p[N_EXP];
#pragma unroll
      for (int e = 0; e < N_EXP; ++e)
        p[e] = fminf(fmaxf(ex[e] / (sum + 1e-8f), 1e-8f), 1.0f);
      int e0 = 0;
#pragma unroll
      for (int e = 1; e < N_EXP; ++e) if (p[e] > p[e0]) e0 = e;
      int e1 = (e0 == 0) ? 1 : 0;
#pragma unroll
      for (int e = 0; e < N_EXP; ++e) if (e != e0 && p[e] > p[e1]) e1 = e;
      float p0 = p[e0], p1 = p[e1];
      float inv = 1.f / (p0 + p1 + 1e-8f);
      s_e0[li] = e0; s_l0[li] = atomicAdd(&lcnt[e0], 1); s_p0[li] = p0 * inv;
      s_e1[li] = e1; s_l1[li] = atomicAdd(&lcnt[e1], 1); s_p1[li] = p1 * inv;
    }
  }
  __syncthreads();
  if (tid < N_EXP) gbase[tid] = atomicAdd(&counts[tid], lcnt[tid]);
  __syncthreads();
  if (tid < 32) {
    const int token = blockIdx.x * 32 + tid;
    int e0 = s_e0[tid], e1 = s_e1[tid];
    int a = gbase[e0] + s_l0[tid];
    int b = gbase[e1] + s_l1[tid];
    ids[e0 * N_TOK + a] = token; wts[e0 * N_TOK + a] = s_p0[tid];
    ids[e1 * N_TOK + b] = token; wts[e1 * N_TOK + b] = s_p1[tid];
    tinfo[token] = make_int4(e0, a, e1, b);       // for combine gather
  }
}

__global__ void offsets_kernel(const int* __restrict__ counts, int* __restrict__ offsets) {
  if (threadIdx.x == 0) {
    int r = 0;
#pragma unroll
    for (int e = 0; e < N_EXP; ++e) { offsets[e] = r; r += counts[e]; }
  }
}

// ====== GEMM1 fused: gathered xb @ Wgu_b^T with gate/up INTERLEAVED B rows, SwiGLU
// in-epilogue via shfl_xor(1) -> H bf16 (compacted rows, pitch 2048).
// The interleave+shfl_xor pairing is HW-verified (round-3 kernel passed with it).
// 128x128 tile (= 64 F-cols x {gate,up}), BK=64, swizzled LDS (0 conflicts).
// XCD decode: expert == chunk; ROW-TILE FASTEST (round-10: FETCH 197->62 MB).
__global__ __launch_bounds__(256, 2) void gemm1_kernel(
    const bf16* __restrict__ xb, const bf16* __restrict__ wgu,
    const int* __restrict__ counts, const int* __restrict__ offsets,
    const int* __restrict__ ids, bf16* __restrict__ H)
{
  const int bid = blockIdx.x;
  const int l   = (bid & 7) * 1024 + (bid >> 3);  // XCD-contiguous logical id
  const int e   = l >> 10;                        // expert == XCD chunk
  const int l2  = l & 1023;
  const int by  = l2 & 31;                        // row tile FASTEST (A resident)
  const int cx  = l2 >> 5;                        // F-col tile 0..31 (64 F cols each)

  const int cnt = counts[e];
  const int row0 = by * 128;
  if (row0 >= cnt) return;
  const int c0h = cx * 64;                        // F-col base in [0, 2048)

  __shared__ bf16 lA[128 * 64];
  __shared__ bf16 lB[128 * 64];

  const int tid  = threadIdx.x;
  const int lane = tid & 63;
  const int w    = tid >> 6;                        // wave 0..3
  const int l8   = lane >> 3;                       // row-within-pass 0..7
  const int ssrc = ((lane & 7) ^ l8) * 8;           // inverse-swizzled k-elem offset

  const int* ide = ids + e * N_TOK;
  const bf16* wge = wgu + (size_t)e * D_GU * D_MODEL;
  const bf16* srcA[4];
  const bf16* srcB[4];
#pragma unroll
  for (int p = 0; p < 4; ++p) {
    const int r = w * 32 + p * 8 + l8;              // LDS tile row 0..127
    srcA[p] = xb + (size_t)ide[min(row0 + r, cnt - 1)] * D_MODEL + ssrc;
    // B rows interleaved: r even = gate col c0h+(r>>1), r odd = up (weight row +D_FF)
    const int wrow = c0h + (r >> 1) + (r & 1) * D_FF;
    srcB[p] = wge + (size_t)wrow * D_MODEL + ssrc;
  }
  char* const dA = (char*)lA + w * 4096;            // + p*1024; dest = base + lane*16
  char* const dB = (char*)lB + w * 4096;

  const int wm = w >> 1;
  const int wn = w & 1;
  const int fr = lane & 15;
  const int fq = lane >> 4;
  const char* pAr = (const char*)lA + (wm * 64 + fr) * 128;   // + fm*2048 + ko
  const char* pBr = (const char*)lB + (wn * 64 + fr) * 128;   // + fn*2048 + ko
  const int ko0 = (fq << 4) ^ ((fr & 7) << 4);                // kk=0 swizzled k-offset
  const int ko1 = (64 + (fq << 4)) ^ ((fr & 7) << 4);         // kk=1

  f32x4 acc[4][4];
#pragma unroll
  for (int i = 0; i < 4; ++i)
#pragma unroll
    for (int j = 0; j < 4; ++j)
#pragma unroll
      for (int k = 0; k < 4; ++k) acc[i][j][k] = 0.f;

  for (int kt = 0; kt < D_MODEL / 64; ++kt) {
#pragma unroll
    for (int p = 0; p < 4; ++p) cp16(dA + p * 1024, srcA[p]);
#pragma unroll
    for (int p = 0; p < 4; ++p) cp16(dB + p * 1024, srcB[p]);
#pragma unroll
    for (int p = 0; p < 4; ++p) { srcA[p] += 64; srcB[p] += 64; }
    __syncthreads();
    {
      bf16x8 a[4];
#pragma unroll
      for (int fm = 0; fm < 4; ++fm) a[fm] = *(const bf16x8*)(pAr + fm * 2048 + ko0);
#pragma unroll
      for (int fn = 0; fn < 4; ++fn) {
        bf16x8 b = *(const bf16x8*)(pBr + fn * 2048 + ko0);
#pragma unroll
        for (int fm = 0; fm < 4; ++fm) acc[fm][fn] = mfma16(a[fm], b, acc[fm][fn]);
      }
#pragma unroll
      for (int fm = 0; fm < 4; ++fm) a[fm] = *(const bf16x8*)(pAr + fm * 2048 + ko1);
#pragma unroll
      for (int fn = 0; fn < 4; ++fn) {
        bf16x8 b = *(const bf16x8*)(pBr + fn * 2048 + ko1);
#pragma unroll
        for (int fm = 0; fm < 4; ++fm) acc[fm][fn] = mfma16(a[fm], b, acc[fm][fn]);
      }
    }
    __syncthreads();
  }

  // ---- epilogue: SwiGLU across interleaved col pairs (even lane = gate, odd = up) ----
  const int hbase = offsets[e] + row0;
#pragma unroll
  for (int fm = 0; fm < 4; ++fm) {
#pragma unroll
    for (int fn = 0; fn < 4; ++fn) {
#pragma unroll
      for (int i = 0; i < 4; ++i) {
        float v = acc[fm][fn][i];
        float o = __shfl_xor(v, 1);               // partner column (gate<->up)
        int m = wm * 64 + fm * 16 + fq * 4 + i;   // C/D: row = quad*4+reg
        if (!(fr & 1) && row0 + m < cnt) {
          float h = v * o / (1.f + expf(-o));     // v=gate, o=up
          int f = c0h + wn * 32 + fn * 8 + (fr >> 1);
          H[(size_t)(hbase + m) * D_FF + f] = (bf16)h;
        }
      }
    }
  }
}

// ====== GEMM2: H (pitch 2048) @ Wd_b^T -> weighted fp32 rows in O (no atomics) ======
// BK=64, swizzled LDS. XCD decode: expert == chunk; row-tile fastest.
__global__ __launch_bounds__(256, 2) void gemm2_kernel(
    const bf16* __restrict__ H, const bf16* __restrict__ wdb,
    const int* __restrict__ counts, const int* __restrict__ offsets,
    const float* __restrict__ wts, float* __restrict__ O)
{
  const int bid = blockIdx.x;
  const int l   = (bid & 7) * 256 + (bid >> 3);
  const int e   = l >> 8;                       // expert == XCD chunk
  const int l2  = l & 255;
  const int by  = l2 & 31;                      // row tile FASTEST
  const int cx  = l2 >> 5;                      // col tile 0..7

  const int cnt = counts[e];
  const int row0 = by * 128;
  if (row0 >= cnt) return;
  const int c0 = cx * 128;                      // output col tile in [0, 1024)
  const int base = offsets[e];

  __shared__ bf16 lA[128 * 64];
  __shared__ bf16 lB[128 * 64];

  const int tid  = threadIdx.x;
  const int lane = tid & 63;
  const int w    = tid >> 6;
  const int l8   = lane >> 3;
  const int ssrc = ((lane & 7) ^ l8) * 8;

  const bf16* wde = wdb + (size_t)e * D_MODEL * D_FF;
  const bf16* srcA[4];
  const bf16* srcB[4];
#pragma unroll
  for (int p = 0; p < 4; ++p) {
    const int r = w * 32 + p * 8 + l8;
    srcA[p] = H   + (size_t)(base + min(row0 + r, cnt - 1)) * D_FF + ssrc;
    srcB[p] = wde + (size_t)(c0 + r) * D_FF + ssrc;
  }
  char* const dA = (char*)lA + w * 4096;
  char* const dB = (char*)lB + w * 4096;

  const int wm = w >> 1;
  const int wn = w & 1;
  const int fr = lane & 15;
  const int fq = lane >> 4;
  const char* pAr = (const char*)lA + (wm * 64 + fr) * 128;
  const char* pBr = (const char*)lB + (wn * 64 + fr) * 128;
  const int ko0 = (fq << 4) ^ ((fr & 7) << 4);
  const int ko1 = (64 + (fq << 4)) ^ ((fr & 7) << 4);

  f32x4 acc[4][4];
#pragma unroll
  for (int i = 0; i < 4; ++i)
#pragma unroll
    for (int j = 0; j < 4; ++j)
#pragma unroll
      for (int k = 0; k < 4; ++k) acc[i][j][k] = 0.f;

  for (int kt = 0; kt < D_FF / 64; ++kt) {      // 32 K-steps
#pragma unroll
    for (int p = 0; p < 4; ++p) cp16(dA + p * 1024, srcA[p]);
#pragma unroll
    for (int p = 0; p < 4; ++p) cp16(dB + p * 1024, srcB[p]);
#pragma unroll
    for (int p = 0; p < 4; ++p) { srcA[p] += 64; srcB[p] += 64; }
    __syncthreads();
    {
      bf16x8 a[4];
#pragma unroll
      for (int fm = 0; fm < 4; ++fm) a[fm] = *(const bf16x8*)(pAr + fm * 2048 + ko0);
#pragma unroll
      for (int fn = 0; fn < 4; ++fn) {
        bf16x8 b = *(const bf16x8*)(pBr + fn * 2048 + ko0);
#pragma unroll
        for (int fm = 0; fm < 4; ++fm) acc[fm][fn] = mfma16(a[fm], b, acc[fm][fn]);
      }
#pragma unroll
      for (int fm = 0; fm < 4; ++fm) a[fm] = *(const bf16x8*)(pAr + fm * 2048 + ko1);
#pragma unroll
      for (int fn = 0; fn < 4; ++fn) {
        bf16x8 b = *(const bf16x8*)(pBr + fn * 2048 + ko1);
#pragma unroll
        for (int fm = 0; fm < 4; ++fm) acc[fm][fn] = mfma16(a[fm], b, acc[fm][fn]);
      }
    }
    __syncthreads();
  }

  const float* wte = wts + e * N_TOK;
#pragma unroll
  for (int fm = 0; fm < 4; ++fm) {
#pragma unroll
    for (int i = 0; i < 4; ++i) {
      int m = wm * 64 + fm * 16 + fq * 4 + i;
      if (row0 + m < cnt) {
        float wgt = wte[row0 + m];
        float* orow = O + (size_t)(base + row0 + m) * D_MODEL;
#pragma unroll
        for (int fn = 0; fn < 4; ++fn) {
          int col = c0 + wn * 64 + fn * 16 + fr;
          orow[col] = wgt * acc[fm][fn][i];     // coalesced, single writer
        }
      }
    }
  }
}

// ====== combine: out[t] = O[off[e0]+p0] + O[off[e1]+p1] (fully overwrites out) ======
__global__ __launch_bounds__(256) void combine_kernel(
    const float* __restrict__ O, const int* __restrict__ offsets,
    const int4* __restrict__ tinfo, float* __restrict__ out)
{
  const int t = blockIdx.x;
  const int4 ti = tinfo[t];
  const float4* r0 = (const float4*)(O + (size_t)(offsets[ti.x] + ti.y) * D_MODEL);
  const float4* r1 = (const float4*)(O + (size_t)(offsets[ti.z] + ti.w) * D_MODEL);
  float4 a = r0[threadIdx.x];
  float4 b = r1[threadIdx.x];
  float4 s; s.x = a.x + b.x; s.y = a.y + b.y; s.z = a.z + b.z; s.w = a.w + b.w;
  ((float4*)(out + (size_t)t * D_MODEL))[threadIdx.x] = s;
}

// =========================================================================================
extern "C" void kernel_launch(void* const* d_in, const int* in_sizes, int n_in,
                              void* d_out, int out_size, void* d_ws, size_t ws_size,
                              hipStream_t stream) {
  const float* x   = (const float*)d_in[0];
  const float* wr  = (const float*)d_in[1];
  const float* wgu = (const float*)d_in[2];
  const float* wd  = (const float*)d_in[3];
  float* out = (float*)d_out;

  char* ws = (char*)d_ws;
  // workspace layout — 136.5 MB total
  int*   counts  = (int*)ws;                             // 32 B
  int*   offsets = (int*)(ws + 64);                      // 32 B
  int*   ids     = (int*)(ws + 4096);                    // 128 KB
  float* wts     = (float*)(ws + 4096 + 131072);         // 128 KB
  int4*  tinfo   = (int4*)(ws + 4096 + 262144);          // 64 KB (ends < 524288)
  bf16*  xb      = (bf16*)(ws + 524288);                 // 8 MB
  bf16*  wgub    = (bf16*)(ws + 524288 + 8388608);       // 64 MB (dead after gemm1)
  float* O       = (float*)(ws + 524288 + 8388608);      // 32 MB alias of wgub (post-gemm1)
  bf16*  H       = (bf16*)(ws + 524288 + 8388608 + 67108864);           // 32 MB
  bf16*  wdb     = (bf16*)(ws + 524288 + 8388608 + 67108864 + 33554432); // 32 MB

  hipMemsetAsync(counts, 0, 64, stream);
  // router (128) + wgu-cvt (1920) + wd-cvt (1024) in one launch
  router_cvt_kernel<<<3072, 256, 0, stream>>>(x, wr, counts, ids, wts, tinfo, xb,
                                              wgu, wgub, wd, wdb);
  offsets_kernel<<<1, 64, 0, stream>>>(counts, offsets);
  gemm1_kernel<<<8192, 256, 0, stream>>>(xb, wgub, counts, offsets, ids, H);
  gemm2_kernel<<<2048, 256, 0, stream>>>(H, wdb, counts, offsets, wts, O);
  combine_kernel<<<N_TOK, 256, 0, stream>>>(O, offsets, tinfo, out);
}

// Round 12
// 401.059 us; speedup vs baseline: 1.0868x; 1.0868x over previous
//
#include <hip/hip_runtime.h>
#include <cstdint>

// ---- problem constants (MoEFeedForward: N=4096, D=1024, F=2048, E=8, top-2) ----
#define N_TOK 4096
#define D_MODEL 1024
#define D_FF 2048
#define D_GU 4096          // 2*D_FF: gate_up row space in w_gate_up
#define N_EXP 8

typedef __bf16 bf16;
typedef __bf16 bf16x8 __attribute__((ext_vector_type(8)));
typedef float f32x4 __attribute__((ext_vector_type(4)));

typedef __attribute__((address_space(1))) void v1_t;
typedef __attribute__((address_space(3))) void v3_t;

// async global->LDS raw copy, 16B/lane; dest = wave-uniform base + lane*16
__device__ __forceinline__ void cp16(void* lds, const void* g) {
  __builtin_amdgcn_global_load_lds((v1_t*)g, (v3_t*)lds, 16, 0, 0);
}

__device__ __forceinline__ f32x4 mfma16(bf16x8 a, bf16x8 b, f32x4 c) {
  return __builtin_amdgcn_mfma_f32_16x16x32_bf16(a, b, c, 0, 0, 0);
}

__device__ __forceinline__ bf16x8 cvt8(float4 a, float4 b) {
  bf16x8 v;
  v[0] = (bf16)a.x; v[1] = (bf16)a.y; v[2] = (bf16)a.z; v[3] = (bf16)a.w;
  v[4] = (bf16)b.x; v[5] = (bf16)b.y; v[6] = (bf16)b.z; v[7] = (bf16)b.w;
  return v;
}

// ======== router + wgu-cvt fused launch (round-10 proven shape) ========
// blocks [0,128): routing + x fp32->bf16, emits tinfo for atomic-free combine.
// blocks [128,2048): wgu fp32->bf16.
__global__ __launch_bounds__(256) void router_cvt_kernel(
    const float* __restrict__ x, const float* __restrict__ wr,
    int* __restrict__ counts, int* __restrict__ ids, float* __restrict__ wts,
    int4* __restrict__ tinfo, bf16* __restrict__ xb,
    const float* __restrict__ wgu, bf16* __restrict__ wgub)
{
  if (blockIdx.x >= 128) {                      // ---- wgu cvt riders (1920 blocks) ----
    const int n8 = (N_EXP * D_GU * D_MODEL) / 8;
    int i = (blockIdx.x - 128) * 256 + threadIdx.x;
    for (; i < n8; i += 1920 * 256) {
      const float4* s = (const float4*)wgu + 2 * (size_t)i;
      ((bf16x8*)wgub)[i] = cvt8(s[0], s[1]);
    }
    return;
  }

  __shared__ int lcnt[N_EXP];
  __shared__ int gbase[N_EXP];
  __shared__ int s_e0[32], s_l0[32], s_e1[32], s_l1[32];
  __shared__ float s_p0[32], s_p1[32];

  const int tid  = threadIdx.x;
  const int wave = tid >> 6;
  const int lane = tid & 63;
  if (tid < N_EXP) lcnt[tid] = 0;
  __syncthreads();

  for (int it = 0; it < 8; ++it) {
    const int li = it * 4 + wave;                 // local token 0..31
    const int token = blockIdx.x * 32 + li;

    const float4* xrow = (const float4*)(x + (size_t)token * D_MODEL + lane * 16);
    float4 x0 = xrow[0], x1 = xrow[1], x2 = xrow[2], x3 = xrow[3];

    bf16* xd = xb + (size_t)token * D_MODEL + lane * 16;
    *(bf16x8*)xd       = cvt8(x0, x1);
    *(bf16x8*)(xd + 8) = cvt8(x2, x3);

    float logit[N_EXP];
#pragma unroll
    for (int e = 0; e < N_EXP; ++e) {
      const float4* wrow = (const float4*)(wr + e * D_MODEL + lane * 16);
      float4 w0 = wrow[0], w1 = wrow[1], w2 = wrow[2], w3 = wrow[3];
      float s = x0.x*w0.x + x0.y*w0.y + x0.z*w0.z + x0.w*w0.w
              + x1.x*w1.x + x1.y*w1.y + x1.z*w1.z + x1.w*w1.w
              + x2.x*w2.x + x2.y*w2.y + x2.z*w2.z + x2.w*w2.w
              + x3.x*w3.x + x3.y*w3.y + x3.z*w3.z + x3.w*w3.w;
#pragma unroll
      for (int m = 32; m >= 1; m >>= 1) s += __shfl_xor(s, m);
      logit[e] = fminf(fmaxf(s, -1e4f), 1e4f);    // reference CLAMP
    }

    if (lane == 0) {
      float mx = logit[0];
#pragma unroll
      for (int e = 1; e < N_EXP; ++e) mx = fmaxf(mx, logit[e]);
      float ex[N_EXP], sum = 0.f;
#pragma unroll
      for (int e = 0; e < N_EXP; ++e) { ex[e] = expf(logit[e] - mx); sum += ex[e]; }
      float p[N_EXP];
#pragma unroll
      for (int e = 0; e < N_EXP; ++e)
        p[e] = fminf(fmaxf(ex[e] / (sum + 1e-8f), 1e-8f), 1.0f);
      int e0 = 0;
#pragma unroll
      for (int e = 1; e < N_EXP; ++e) if (p[e] > p[e0]) e0 = e;
      int e1 = (e0 == 0) ? 1 : 0;
#pragma unroll
      for (int e = 0; e < N_EXP; ++e) if (e != e0 && p[e] > p[e1]) e1 = e;
      float p0 = p[e0], p1 = p[e1];
      float inv = 1.f / (p0 + p1 + 1e-8f);
      s_e0[li] = e0; s_l0[li] = atomicAdd(&lcnt[e0], 1); s_p0[li] = p0 * inv;
      s_e1[li] = e1; s_l1[li] = atomicAdd(&lcnt[e1], 1); s_p1[li] = p1 * inv;
    }
  }
  __syncthreads();
  if (tid < N_EXP) gbase[tid] = atomicAdd(&counts[tid], lcnt[tid]);
  __syncthreads();
  if (tid < 32) {
    const int token = blockIdx.x * 32 + tid;
    int e0 = s_e0[tid], e1 = s_e1[tid];
    int a = gbase[e0] + s_l0[tid];
    int b = gbase[e1] + s_l1[tid];
    ids[e0 * N_TOK + a] = token; wts[e0 * N_TOK + a] = s_p0[tid];
    ids[e1 * N_TOK + b] = token; wts[e1 * N_TOK + b] = s_p1[tid];
    tinfo[token] = make_int4(e0, a, e1, b);       // for combine gather
  }
}

__global__ void offsets_kernel(const int* __restrict__ counts, int* __restrict__ offsets) {
  if (threadIdx.x == 0) {
    int r = 0;
#pragma unroll
    for (int e = 0; e < N_EXP; ++e) { offsets[e] = r; r += counts[e]; }
  }
}

// ====== GEMM1 fused: gathered xb @ Wgu_b^T with gate/up INTERLEAVED B rows, SwiGLU
// in-epilogue via shfl_xor(1) + FAST MATH (v_exp_f32 + v_rcp_f32, ~6 instrs/elem
// vs libm expf+div ~40 — round-11's +30us epilogue cost) -> H bf16 (pitch 2048).
// 128x128 tile (= 64 F-cols x {gate,up}), BK=64, swizzled LDS (0 conflicts).
// XCD decode: expert == chunk; ROW-TILE FASTEST. blocks >= 8192: wd-cvt riders
// (gemm1 runs at HBM 9% -- riders absorb free bandwidth).
__global__ __launch_bounds__(256, 2) void gemm1_kernel(
    const bf16* __restrict__ xb, const bf16* __restrict__ wgu,
    const int* __restrict__ counts, const int* __restrict__ offsets,
    const int* __restrict__ ids, bf16* __restrict__ H,
    const float* __restrict__ wd, bf16* __restrict__ wdb)
{
  if (blockIdx.x >= 8192) {                     // ---- wd cvt riders (1024 blocks) ----
    const int n8 = (N_EXP * D_MODEL * D_FF) / 8;
    int i = (blockIdx.x - 8192) * 256 + threadIdx.x;
    for (; i < n8; i += 1024 * 256) {
      const float4* s = (const float4*)wd + 2 * (size_t)i;
      ((bf16x8*)wdb)[i] = cvt8(s[0], s[1]);
    }
    return;
  }
  const int bid = blockIdx.x;
  const int l   = (bid & 7) * 1024 + (bid >> 3);  // XCD-contiguous logical id
  const int e   = l >> 10;                        // expert == XCD chunk
  const int l2  = l & 1023;
  const int by  = l2 & 31;                        // row tile FASTEST (A resident)
  const int cx  = l2 >> 5;                        // F-col tile 0..31 (64 F cols each)

  const int cnt = counts[e];
  const int row0 = by * 128;
  if (row0 >= cnt) return;
  const int c0h = cx * 64;                        // F-col base in [0, 2048)

  __shared__ bf16 lA[128 * 64];
  __shared__ bf16 lB[128 * 64];

  const int tid  = threadIdx.x;
  const int lane = tid & 63;
  const int w    = tid >> 6;                        // wave 0..3
  const int l8   = lane >> 3;                       // row-within-pass 0..7
  const int ssrc = ((lane & 7) ^ l8) * 8;           // inverse-swizzled k-elem offset

  const int* ide = ids + e * N_TOK;
  const bf16* wge = wgu + (size_t)e * D_GU * D_MODEL;
  const bf16* srcA[4];
  const bf16* srcB[4];
#pragma unroll
  for (int p = 0; p < 4; ++p) {
    const int r = w * 32 + p * 8 + l8;              // LDS tile row 0..127
    srcA[p] = xb + (size_t)ide[min(row0 + r, cnt - 1)] * D_MODEL + ssrc;
    // B rows interleaved: r even = gate col c0h+(r>>1), r odd = up (weight row +D_FF)
    const int wrow = c0h + (r >> 1) + (r & 1) * D_FF;
    srcB[p] = wge + (size_t)wrow * D_MODEL + ssrc;
  }
  char* const dA = (char*)lA + w * 4096;            // + p*1024; dest = base + lane*16
  char* const dB = (char*)lB + w * 4096;

  const int wm = w >> 1;
  const int wn = w & 1;
  const int fr = lane & 15;
  const int fq = lane >> 4;
  const char* pAr = (const char*)lA + (wm * 64 + fr) * 128;   // + fm*2048 + ko
  const char* pBr = (const char*)lB + (wn * 64 + fr) * 128;   // + fn*2048 + ko
  const int ko0 = (fq << 4) ^ ((fr & 7) << 4);                // kk=0 swizzled k-offset
  const int ko1 = (64 + (fq << 4)) ^ ((fr & 7) << 4);         // kk=1

  f32x4 acc[4][4];
#pragma unroll
  for (int i = 0; i < 4; ++i)
#pragma unroll
    for (int j = 0; j < 4; ++j)
#pragma unroll
      for (int k = 0; k < 4; ++k) acc[i][j][k] = 0.f;

  for (int kt = 0; kt < D_MODEL / 64; ++kt) {
#pragma unroll
    for (int p = 0; p < 4; ++p) cp16(dA + p * 1024, srcA[p]);
#pragma unroll
    for (int p = 0; p < 4; ++p) cp16(dB + p * 1024, srcB[p]);
#pragma unroll
    for (int p = 0; p < 4; ++p) { srcA[p] += 64; srcB[p] += 64; }
    __syncthreads();
    {
      bf16x8 a[4];
#pragma unroll
      for (int fm = 0; fm < 4; ++fm) a[fm] = *(const bf16x8*)(pAr + fm * 2048 + ko0);
#pragma unroll
      for (int fn = 0; fn < 4; ++fn) {
        bf16x8 b = *(const bf16x8*)(pBr + fn * 2048 + ko0);
#pragma unroll
        for (int fm = 0; fm < 4; ++fm) acc[fm][fn] = mfma16(a[fm], b, acc[fm][fn]);
      }
#pragma unroll
      for (int fm = 0; fm < 4; ++fm) a[fm] = *(const bf16x8*)(pAr + fm * 2048 + ko1);
#pragma unroll
      for (int fn = 0; fn < 4; ++fn) {
        bf16x8 b = *(const bf16x8*)(pBr + fn * 2048 + ko1);
#pragma unroll
        for (int fm = 0; fm < 4; ++fm) acc[fm][fn] = mfma16(a[fm], b, acc[fm][fn]);
      }
    }
    __syncthreads();
  }

  // ---- epilogue: SwiGLU, fast math. even lane = gate(v), odd lane = up; h computed
  // unconditionally (mask only on store), exp via v_exp_f32, div via v_rcp_f32.
  const int hbase = offsets[e] + row0;
#pragma unroll
  for (int fm = 0; fm < 4; ++fm) {
#pragma unroll
    for (int fn = 0; fn < 4; ++fn) {
#pragma unroll
      for (int i = 0; i < 4; ++i) {
        float v = acc[fm][fn][i];
        float o = __shfl_xor(v, 1);               // partner column (gate<->up)
        float h = v * o * __builtin_amdgcn_rcpf(1.f + __expf(-o)); // v=gate, o=up
        int m = wm * 64 + fm * 16 + fq * 4 + i;   // C/D: row = quad*4+reg
        if (!(fr & 1) && row0 + m < cnt) {
          int f = c0h + wn * 32 + fn * 8 + (fr >> 1);
          H[(size_t)(hbase + m) * D_FF + f] = (bf16)h;
        }
      }
    }
  }
}

// ====== GEMM2: H (pitch 2048) @ Wd_b^T -> weighted fp32 rows in O (no atomics) ======
// BK=64, swizzled LDS. XCD decode: expert == chunk; row-tile fastest.
__global__ __launch_bounds__(256, 2) void gemm2_kernel(
    const bf16* __restrict__ H, const bf16* __restrict__ wdb,
    const int* __restrict__ counts, const int* __restrict__ offsets,
    const float* __restrict__ wts, float* __restrict__ O)
{
  const int bid = blockIdx.x;
  const int l   = (bid & 7) * 256 + (bid >> 3);
  const int e   = l >> 8;                       // expert == XCD chunk
  const int l2  = l & 255;
  const int by  = l2 & 31;                      // row tile FASTEST
  const int cx  = l2 >> 5;                      // col tile 0..7

  const int cnt = counts[e];
  const int row0 = by * 128;
  if (row0 >= cnt) return;
  const int c0 = cx * 128;                      // output col tile in [0, 1024)
  const int base = offsets[e];

  __shared__ bf16 lA[128 * 64];
  __shared__ bf16 lB[128 * 64];

  const int tid  = threadIdx.x;
  const int lane = tid & 63;
  const int w    = tid >> 6;
  const int l8   = lane >> 3;
  const int ssrc = ((lane & 7) ^ l8) * 8;

  const bf16* wde = wdb + (size_t)e * D_MODEL * D_FF;
  const bf16* srcA[4];
  const bf16* srcB[4];
#pragma unroll
  for (int p = 0; p < 4; ++p) {
    const int r = w * 32 + p * 8 + l8;
    srcA[p] = H   + (size_t)(base + min(row0 + r, cnt - 1)) * D_FF + ssrc;
    srcB[p] = wde + (size_t)(c0 + r) * D_FF + ssrc;
  }
  char* const dA = (char*)lA + w * 4096;
  char* const dB = (char*)lB + w * 4096;

  const int wm = w >> 1;
  const int wn = w & 1;
  const int fr = lane & 15;
  const int fq = lane >> 4;
  const char* pAr = (const char*)lA + (wm * 64 + fr) * 128;
  const char* pBr = (const char*)lB + (wn * 64 + fr) * 128;
  const int ko0 = (fq << 4) ^ ((fr & 7) << 4);
  const int ko1 = (64 + (fq << 4)) ^ ((fr & 7) << 4);

  f32x4 acc[4][4];
#pragma unroll
  for (int i = 0; i < 4; ++i)
#pragma unroll
    for (int j = 0; j < 4; ++j)
#pragma unroll
      for (int k = 0; k < 4; ++k) acc[i][j][k] = 0.f;

  for (int kt = 0; kt < D_FF / 64; ++kt) {      // 32 K-steps
#pragma unroll
    for (int p = 0; p < 4; ++p) cp16(dA + p * 1024, srcA[p]);
#pragma unroll
    for (int p = 0; p < 4; ++p) cp16(dB + p * 1024, srcB[p]);
#pragma unroll
    for (int p = 0; p < 4; ++p) { srcA[p] += 64; srcB[p] += 64; }
    __syncthreads();
    {
      bf16x8 a[4];
#pragma unroll
      for (int fm = 0; fm < 4; ++fm) a[fm] = *(const bf16x8*)(pAr + fm * 2048 + ko0);
#pragma unroll
      for (int fn = 0; fn < 4; ++fn) {
        bf16x8 b = *(const bf16x8*)(pBr + fn * 2048 + ko0);
#pragma unroll
        for (int fm = 0; fm < 4; ++fm) acc[fm][fn] = mfma16(a[fm], b, acc[fm][fn]);
      }
#pragma unroll
      for (int fm = 0; fm < 4; ++fm) a[fm] = *(const bf16x8*)(pAr + fm * 2048 + ko1);
#pragma unroll
      for (int fn = 0; fn < 4; ++fn) {
        bf16x8 b = *(const bf16x8*)(pBr + fn * 2048 + ko1);
#pragma unroll
        for (int fm = 0; fm < 4; ++fm) acc[fm][fn] = mfma16(a[fm], b, acc[fm][fn]);
      }
    }
    __syncthreads();
  }

  const float* wte = wts + e * N_TOK;
#pragma unroll
  for (int fm = 0; fm < 4; ++fm) {
#pragma unroll
    for (int i = 0; i < 4; ++i) {
      int m = wm * 64 + fm * 16 + fq * 4 + i;
      if (row0 + m < cnt) {
        float wgt = wte[row0 + m];
        float* orow = O + (size_t)(base + row0 + m) * D_MODEL;
#pragma unroll
        for (int fn = 0; fn < 4; ++fn) {
          int col = c0 + wn * 64 + fn * 16 + fr;
          orow[col] = wgt * acc[fm][fn][i];     // coalesced, single writer
        }
      }
    }
  }
}

// ====== combine: out[t] = O[off[e0]+p0] + O[off[e1]+p1] (fully overwrites out) ======
__global__ __launch_bounds__(256) void combine_kernel(
    const float* __restrict__ O, const int* __restrict__ offsets,
    const int4* __restrict__ tinfo, float* __restrict__ out)
{
  const int t = blockIdx.x;
  const int4 ti = tinfo[t];
  const float4* r0 = (const float4*)(O + (size_t)(offsets[ti.x] + ti.y) * D_MODEL);
  const float4* r1 = (const float4*)(O + (size_t)(offsets[ti.z] + ti.w) * D_MODEL);
  float4 a = r0[threadIdx.x];
  float4 b = r1[threadIdx.x];
  float4 s; s.x = a.x + b.x; s.y = a.y + b.y; s.z = a.z + b.z; s.w = a.w + b.w;
  ((float4*)(out + (size_t)t * D_MODEL))[threadIdx.x] = s;
}

// =========================================================================================
extern "C" void kernel_launch(void* const* d_in, const int* in_sizes, int n_in,
                              void* d_out, int out_size, void* d_ws, size_t ws_size,
                              hipStream_t stream) {
  const float* x   = (const float*)d_in[0];
  const float* wr  = (const float*)d_in[1];
  const float* wgu = (const float*)d_in[2];
  const float* wd  = (const float*)d_in[3];
  float* out = (float*)d_out;

  char* ws = (char*)d_ws;
  // workspace layout — 136.5 MB total
  int*   counts  = (int*)ws;                             // 32 B
  int*   offsets = (int*)(ws + 64);                      // 32 B
  int*   ids     = (int*)(ws + 4096);                    // 128 KB
  float* wts     = (float*)(ws + 4096 + 131072);         // 128 KB
  int4*  tinfo   = (int4*)(ws + 4096 + 262144);          // 64 KB (ends < 524288)
  bf16*  xb      = (bf16*)(ws + 524288);                 // 8 MB
  bf16*  wgub    = (bf16*)(ws + 524288 + 8388608);       // 64 MB (dead after gemm1)
  float* O       = (float*)(ws + 524288 + 8388608);      // 32 MB alias of wgub (post-gemm1)
  bf16*  H       = (bf16*)(ws + 524288 + 8388608 + 67108864);           // 32 MB
  bf16*  wdb     = (bf16*)(ws + 524288 + 8388608 + 67108864 + 33554432); // 32 MB

  hipMemsetAsync(counts, 0, 64, stream);
  // router (128) + wgu-cvt (1920) in one launch
  router_cvt_kernel<<<2048, 256, 0, stream>>>(x, wr, counts, ids, wts, tinfo, xb, wgu, wgub);
  offsets_kernel<<<1, 64, 0, stream>>>(counts, offsets);
  // gemm1 (8192 blocks) + wd-cvt riders (1024 blocks)
  gemm1_kernel<<<9216, 256, 0, stream>>>(xb, wgub, counts, offsets, ids, H, wd, wdb);
  gemm2_kernel<<<2048, 256, 0, stream>>>(H, wdb, counts, offsets, wts, O);
  combine_kernel<<<N_TOK, 256, 0, stream>>>(O, offsets, tinfo, out);
}